// Round 10
// baseline (65.747 us; speedup 1.0000x reference)
//
#include <hip/hip_runtime.h>
#include <hip/hip_fp16.h>
#include <math.h>

#define BB 8
#define HH 128
#define WW 128
#define CC 64
#define KK 9
#define OUTC 64
#define TW 16
#define KTOT 576          // kappa = k*64 + c
#define NELEM (BB*HH*WW*CC)
#define XSW 3456          // ushorts in the f16 x-tile: 3*18*64

typedef __attribute__((ext_vector_type(8))) _Float16 half8v;
typedef __attribute__((ext_vector_type(4))) float float4v;

static __device__ __forceinline__ unsigned short f2h(float f) {
    return __half_as_ushort(__float2half(f));   // RNE
}
static __device__ __forceinline__ unsigned h2bits(float f) {
    __half2 h = __float2half2_rn(f);
    unsigned r; __builtin_memcpy(&r, &h, 4); return r;
}
static __device__ __forceinline__ __half2 bits2h(unsigned w) {
    __half2 h; __builtin_memcpy(&h, &w, 4); return h;
}

// Swizzled MFMA-fragment LDS offset (ushort units) for cols (pixel p, kappa).
static __device__ __forceinline__ int frag_addr(int p, int kappa) {
    int chunk = kappa >> 3;
    return ((chunk >> 2) << 9) + ((chunk & 3) << 7) + ((p ^ (chunk & 7)) << 3) + (kappa & 7);
}

// ---- prep: weights -> f16 FRAGMENT-ORDER panels; x -> f16 copy ----
__global__ __launch_bounds__(256) void prep_all(
    const float* __restrict__ x, const float* __restrict__ offk,
    const float* __restrict__ mk, const float* __restrict__ filt,
    unsigned short* __restrict__ fbf,  // [4*18*512]
    unsigned short* __restrict__ wcf,  // [2*18*512]
    unsigned short* __restrict__ xf,   // f16 copy of x
    int do_x)
{
    int bid = blockIdx.x, tid = threadIdx.x;
    if (bid < 144) {
        int j = bid * 256 + tid;                 // 36864 total
        {
            int w = j / 9216, rem = j - w * 9216;
            int ks = rem >> 9, ln = (rem >> 3) & 63, sj = rem & 7;
            int pl = ln & 15, lg = ln >> 4;
            int o = w * 16 + pl, kap = ks * 32 + lg * 8 + sj;
            int k = kap >> 6, c = kap & 63;
            fbf[j] = f2h(filt[(o * CC + c) * KK + k]);
        }
        if (j < 18432) {
            int nh = j / 9216, rem = j - nh * 9216;
            int ks = rem >> 9, ln = (rem >> 3) & 63, sj = rem & 7;
            int pl = ln & 15, lg = ln >> 4;
            int o = nh * 16 + pl, kap = ks * 32 + lg * 8 + sj;
            int k = kap >> 6, c = kap & 63;
            float v = 0.f;
            if (o < 18)      v = offk[(k * CC + c) * 18 + o];
            else if (o < 27) v = mk[(k * CC + c) * 9 + (o - 18)];
            wcf[j] = f2h(v);
        }
        return;
    }
    if (!do_x) return;
    int i = (bid - 144) * 256 + tid;          // 8 elems/thread, 4096 blocks exact
    const float* src = x + (size_t)i * 8;
    float4 a = *(const float4*)(src);
    float4 c = *(const float4*)(src + 4);
    float v[8] = {a.x, a.y, a.z, a.w, c.x, c.y, c.z, c.w};
    unsigned q[4];
#pragma unroll
    for (int j = 0; j < 4; ++j)
        q[j] = (unsigned)f2h(v[2 * j]) | ((unsigned)f2h(v[2 * j + 1]) << 16);
    *(uint4*)(xf + (size_t)i * 8) = make_uint4(q[0], q[1], q[2], q[3]);
}

template<int HASB>
__global__ __launch_bounds__(256, 7) void deform_conv_fused(
    const float* __restrict__ x,
    const unsigned short* __restrict__ xf,
    const unsigned short* __restrict__ fbf,
    const unsigned short* __restrict__ wcf,
    float* __restrict__ out)
{
    // ims (cols, 18432B) overlays the conv x-tile (6912B f16, single plane).
    __shared__ __align__(16) unsigned short ims[TW * KTOT];
    __shared__ __align__(16) union UU {
        float ps2[4][TW][18];                      // conv partials
        struct { int4 c[144]; uint4 w[144]; } gs;  // gather setup (packed half2 w)
    } u;

    const int tid  = threadIdx.x;
    const int lane = tid & 63;
    const int wave = tid >> 6;
    const int pl = lane & 15;
    const int lg = lane >> 4;
    const int off_e = lg * 128 + ((pl ^ lg) << 3);
    const int off_o = lg * 128 + ((pl ^ (lg + 4)) << 3);

    // XCD swizzle: 8192 blocks, each XCD owns one image b.
    const int swz = (blockIdx.x & 7) * 1024 + (blockIdx.x >> 3);
    const int bw = swz & 7;
    const int h  = (swz >> 3) & 127;
    const int b  = swz >> 10;
    const int w0 = bw * TW;

    // -------- stage x tile [3 rows][18 px][64 ch] f16, coalesced -----------------
    // LDS index swizzle: channel chunk XOR (px&7) -> conv ds_reads <=2-way.
#pragma unroll
    for (int it = 0; it < 2; ++it) {
        int e = tid + it * 256;
        if (it == 1 && e >= 432) break;
        int r    = (e >= 288) ? 2 : (e >= 144) ? 1 : 0;
        int rem2 = e - r * 144;
        int px   = rem2 >> 3;
        int c8   = rem2 & 7;
        int y = h + r - 1, xg = w0 + px - 1;
        int lidx = (r * 18 + px) * 64 + ((c8 * 8) ^ ((px & 7) << 3));
        uint4 val = make_uint4(0u, 0u, 0u, 0u);
        if ((unsigned)y < (unsigned)HH && (unsigned)xg < (unsigned)WW) {
            int goff = ((b * HH + y) * WW + xg) * CC + c8 * 8;
            if (HASB) {
                val = *(const uint4*)(xf + goff);
            } else {
                float4 v0 = *(const float4*)(x + goff);
                float4 v1 = *(const float4*)(x + goff + 4);
                float vv[8] = {v0.x, v0.y, v0.z, v0.w, v1.x, v1.y, v1.z, v1.w};
                unsigned q[4];
#pragma unroll
                for (int j = 0; j < 4; ++j)
                    q[j] = (unsigned)f2h(vv[2 * j]) | ((unsigned)f2h(vv[2 * j + 1]) << 16);
                val = make_uint4(q[0], q[1], q[2], q[3]);
            }
        }
        *(uint4*)(ims + lidx) = val;
    }
    __syncthreads();

    // -------- conv via MFMA (f16): A from LDS tile, B contiguous panel -----------
    const int nh = wave & 1, kh = wave >> 1;
    float4v acc = {0.f, 0.f, 0.f, 0.f};
    __builtin_amdgcn_s_setprio(1);
#pragma unroll
    for (int ks9 = 0; ks9 < 9; ++ks9) {
        const int ksg = kh * 9 + ks9;
        const int tap = ksg >> 1;
        const int cb  = (ksg & 1) * 32 + lg * 8;
        const int ky = tap / 3, kx = tap - ky * 3;
        const int px = pl + kx;
        const int base = (ky * 18 + px) * 64 + (cb ^ ((px & 7) << 3));
        half8v af = *(const half8v*)(ims + base);
        half8v bv = *(const half8v*)(wcf + ((nh * 18 + ksg) << 9) + (lane << 3));
        acc = __builtin_amdgcn_mfma_f32_16x16x32_f16(af, bv, acc, 0, 0, 0);
    }
    __builtin_amdgcn_s_setprio(0);
#pragma unroll
    for (int r = 0; r < 4; ++r)
        u.ps2[wave][lg * 4 + r][pl] = acc[r];

    // prefetch first einsum B-fragments (contiguous panel, live across barriers)
    const unsigned short* Bpf = fbf + ((wave * 18) << 9) + (lane << 3);
    half8v bp0 = *(const half8v*)(Bpf);
    half8v bp1 = *(const half8v*)(Bpf + 512);
    __syncthreads();

    // -------- setup part 1: read conv partials ------------------------------------
    const int sp = tid / 9, sk = tid - (tid / 9) * 9;
    float s_dy = 0.f, s_dx = 0.f, s_ml = 0.f;
    if (tid < 144) {
        auto rd = [&](int o) {
            int nhh = o >> 4, col = o & 15;
            return u.ps2[nhh][sp][col] + u.ps2[2 + nhh][sp][col];
        };
        s_dy = rd(2 * sk); s_dx = rd(2 * sk + 1); s_ml = rd(18 + sk);
    }
    __syncthreads();   // ps2 reads done; gs overlay + ims overwrite now safe

    // -------- setup part 2: corner bases + folded packed-f16 weights -> gs --------
    if (tid < 144) {
        float m  = 1.f / (1.f + __expf(-s_ml));
        float py = (float)(h + (sk / 3) - 1) + s_dy;
        float px = (float)(w0 + sp + (sk % 3) - 1) + s_dx;
        float y0 = floorf(py), x0 = floorf(px);
        float ly = py - y0, lx = px - x0;
        bool vy0 = (y0 >= 0.f)  && (y0 <= 127.f);
        bool vy1 = (y0 >= -1.f) && (y0 <= 126.f);
        bool vx0 = (x0 >= 0.f)  && (x0 <= 127.f);
        bool vx1 = (x0 >= -1.f) && (x0 <= 126.f);
        float wy0 = 1.f - ly, wx0 = 1.f - lx;
        int iy0 = (int)fminf(fmaxf(y0, 0.f), 127.f);
        int iy1 = (int)fminf(fmaxf(y0 + 1.f, 0.f), 127.f);
        int ix0 = (int)fminf(fmaxf(x0, 0.f), 127.f);
        int ix1 = (int)fminf(fmaxf(x0 + 1.f, 0.f), 127.f);
        int base = b * (HH * WW * CC);
        u.gs.c[tid] = make_int4(base + (iy0 * WW + ix0) * CC,
                                base + (iy0 * WW + ix1) * CC,
                                base + (iy1 * WW + ix0) * CC,
                                base + (iy1 * WW + ix1) * CC);
        u.gs.w[tid] = make_uint4(h2bits((vy0 && vx0) ? wy0 * wx0 * m : 0.f),
                                 h2bits((vy0 && vx1) ? wy0 * lx  * m : 0.f),
                                 h2bits((vy1 && vx0) ? ly  * wx0 * m : 0.f),
                                 h2bits((vy1 && vx1) ? ly  * lx  * m : 0.f));
    }
    __syncthreads();

    // -------- gather: 1152 tasks (pair, c8); packed-f16 math, zero repack ---------
    if (HASB) {
        for (int t = tid; t < 1152; t += 256) {
            int pair = t >> 3, c8 = t & 7;
            int p = pair / 9, k = pair - (pair / 9) * 9;
            int4  cc = u.gs.c[pair];
            uint4 wq = u.gs.w[pair];
            __half2 w0 = bits2h(wq.x), w1 = bits2h(wq.y);
            __half2 w2 = bits2h(wq.z), w3 = bits2h(wq.w);
            int co = c8 * 8;
            uint4 u00 = *(const uint4*)(xf + cc.x + co);
            uint4 u01 = *(const uint4*)(xf + cc.y + co);
            uint4 u10 = *(const uint4*)(xf + cc.z + co);
            uint4 u11 = *(const uint4*)(xf + cc.w + co);
            const unsigned* a00 = (const unsigned*)&u00;
            const unsigned* a01 = (const unsigned*)&u01;
            const unsigned* a10 = (const unsigned*)&u10;
            const unsigned* a11 = (const unsigned*)&u11;
            unsigned qq[4];
#pragma unroll
            for (int jj = 0; jj < 4; ++jj) {
                __half2 acc2 = __hmul2(bits2h(a00[jj]), w0);
                acc2 = __hfma2(bits2h(a01[jj]), w1, acc2);
                acc2 = __hfma2(bits2h(a10[jj]), w2, acc2);
                acc2 = __hfma2(bits2h(a11[jj]), w3, acc2);
                __builtin_memcpy(&qq[jj], &acc2, 4);
            }
            *(uint4*)(ims + frag_addr(p, k * 64 + co)) = make_uint4(qq[0], qq[1], qq[2], qq[3]);
        }
    } else {
        for (int t = tid; t < 1152; t += 256) {
            int pair = t >> 3, c8 = t & 7;
            int p = pair / 9, k = pair - (pair / 9) * 9;
            int4  cc = u.gs.c[pair];
            uint4 wq = u.gs.w[pair];
            float wx = __half2float(bits2h(wq.x).x);
            float wy = __half2float(bits2h(wq.y).x);
            float wz = __half2float(bits2h(wq.z).x);
            float ww = __half2float(bits2h(wq.w).x);
            int co = c8 * 8;
            float r[8];
#pragma unroll
            for (int half = 0; half < 2; ++half) {
                float4 v00 = *(const float4*)(x + cc.x + co + half * 4);
                float4 v01 = *(const float4*)(x + cc.y + co + half * 4);
                float4 v10 = *(const float4*)(x + cc.z + co + half * 4);
                float4 v11 = *(const float4*)(x + cc.w + co + half * 4);
                r[half * 4 + 0] = wx * v00.x + wy * v01.x + wz * v10.x + ww * v11.x;
                r[half * 4 + 1] = wx * v00.y + wy * v01.y + wz * v10.y + ww * v11.y;
                r[half * 4 + 2] = wx * v00.z + wy * v01.z + wz * v10.z + ww * v11.z;
                r[half * 4 + 3] = wx * v00.w + wy * v01.w + wz * v10.w + ww * v11.w;
            }
            unsigned qq[4];
#pragma unroll
            for (int jj = 0; jj < 4; ++jj)
                qq[jj] = (unsigned)f2h(r[2 * jj]) | ((unsigned)f2h(r[2 * jj + 1]) << 16);
            *(uint4*)(ims + frag_addr(p, k * 64 + co)) = make_uint4(qq[0], qq[1], qq[2], qq[3]);
        }
    }
    __syncthreads();

    // -------- main einsum (f16): wave owns 16 outputs, even/odd accumulators ------
    {
        float4v accA = {0.f, 0.f, 0.f, 0.f}, accB = {0.f, 0.f, 0.f, 0.f};
        __builtin_amdgcn_s_setprio(1);
#pragma unroll
        for (int ks = 0; ks < 18; ++ks) {
            half8v a  = *(const half8v*)(ims + ks * 512 + ((ks & 1) ? off_o : off_e));
            half8v bv = (ks == 0) ? bp0 : (ks == 1) ? bp1
                      : *(const half8v*)(Bpf + (ks << 9));
            if (ks & 1) accB = __builtin_amdgcn_mfma_f32_16x16x32_f16(a, bv, accB, 0, 0, 0);
            else        accA = __builtin_amdgcn_mfma_f32_16x16x32_f16(a, bv, accA, 0, 0, 0);
        }
        __builtin_amdgcn_s_setprio(0);
        const int o = wave * 16 + pl;
        const size_t rowbase = (size_t)(b * HH + h) * WW + w0;
#pragma unroll
        for (int r = 0; r < 4; ++r) {
            int p = lg * 4 + r;
            out[(rowbase + p) * OUTC + o] = accA[r] + accB[r];
        }
    }
}

extern "C" void kernel_launch(void* const* d_in, const int* in_sizes, int n_in,
                              void* d_out, int out_size, void* d_ws, size_t ws_size,
                              hipStream_t stream) {
    const float* x    = (const float*)d_in[0];
    const float* offk = (const float*)d_in[1];
    const float* mk   = (const float*)d_in[2];
    const float* filt = (const float*)d_in[3];
    float* out = (float*)d_out;
    unsigned short* fbf = (unsigned short*)d_ws;                // 73728 B
    unsigned short* wcf = fbf + OUTC * KTOT;                    // 36864 B
    unsigned short* xf  = wcf + 32 * KTOT;                      // 16.78 MB
    size_t need = (size_t)(OUTC + 32) * KTOT * 2 + (size_t)NELEM * 2;
    int do_x = (ws_size >= need) ? 1 : 0;
    prep_all<<<144 + (do_x ? 4096 : 0), 256, 0, stream>>>(x, offk, mk, filt, fbf, wcf, xf, do_x);
    if (do_x)
        deform_conv_fused<1><<<BB * HH * (WW / TW), 256, 0, stream>>>(x, xf, fbf, wcf, out);
    else
        deform_conv_fused<0><<<BB * HH * (WW / TW), 256, 0, stream>>>(x, xf, fbf, wcf, out);
}

// Round 11
// 65.210 us; speedup vs baseline: 1.0082x; 1.0082x over previous
//
#include <hip/hip_runtime.h>
#include <hip/hip_fp16.h>
#include <math.h>

#define BB 8
#define HH 128
#define WW 128
#define CC 64
#define KK 9
#define OUTC 64
#define TW 16
#define KTOT 576          // kappa = k*64 + c
#define NELEM (BB*HH*WW*CC)

typedef __attribute__((ext_vector_type(8))) _Float16 half8v;
typedef __attribute__((ext_vector_type(4))) float float4v;

static __device__ __forceinline__ unsigned short f2h(float f) {
    return __half_as_ushort(__float2half(f));   // RNE
}
static __device__ __forceinline__ unsigned h2bits(float f) {
    __half2 h = __float2half2_rn(f);
    unsigned r; __builtin_memcpy(&r, &h, 4); return r;
}
static __device__ __forceinline__ __half2 bits2h(unsigned w) {
    __half2 h; __builtin_memcpy(&h, &w, 4); return h;
}

// Swizzled MFMA-fragment LDS offset (ushort units) for cols (pixel p, kappa).
static __device__ __forceinline__ int frag_addr(int p, int kappa) {
    int chunk = kappa >> 3;
    return ((chunk >> 2) << 9) + ((chunk & 3) << 7) + ((p ^ (chunk & 7)) << 3) + (kappa & 7);
}

// ---- prep: weights -> f16 FRAGMENT-ORDER panels; x -> f16 copy ----
__global__ __launch_bounds__(256) void prep_all(
    const float* __restrict__ x, const float* __restrict__ offk,
    const float* __restrict__ mk, const float* __restrict__ filt,
    unsigned short* __restrict__ fbf,  // [4*18*512]
    unsigned short* __restrict__ wcf,  // [2*18*512]
    unsigned short* __restrict__ xf,   // f16 copy of x
    int do_x)
{
    int bid = blockIdx.x, tid = threadIdx.x;
    if (bid < 144) {
        int j = bid * 256 + tid;                 // 36864 total
        {
            int w = j / 9216, rem = j - w * 9216;
            int ks = rem >> 9, ln = (rem >> 3) & 63, sj = rem & 7;
            int pl = ln & 15, lg = ln >> 4;
            int o = w * 16 + pl, kap = ks * 32 + lg * 8 + sj;
            int k = kap >> 6, c = kap & 63;
            fbf[j] = f2h(filt[(o * CC + c) * KK + k]);
        }
        if (j < 18432) {
            int nh = j / 9216, rem = j - nh * 9216;
            int ks = rem >> 9, ln = (rem >> 3) & 63, sj = rem & 7;
            int pl = ln & 15, lg = ln >> 4;
            int o = nh * 16 + pl, kap = ks * 32 + lg * 8 + sj;
            int k = kap >> 6, c = kap & 63;
            float v = 0.f;
            if (o < 18)      v = offk[(k * CC + c) * 18 + o];
            else if (o < 27) v = mk[(k * CC + c) * 9 + (o - 18)];
            wcf[j] = f2h(v);
        }
        return;
    }
    if (!do_x) return;
    int i = (bid - 144) * 256 + tid;          // 8 elems/thread, 4096 blocks exact
    const float* src = x + (size_t)i * 8;
    float4 a = *(const float4*)(src);
    float4 c = *(const float4*)(src + 4);
    float v[8] = {a.x, a.y, a.z, a.w, c.x, c.y, c.z, c.w};
    unsigned q[4];
#pragma unroll
    for (int j = 0; j < 4; ++j)
        q[j] = (unsigned)f2h(v[2 * j]) | ((unsigned)f2h(v[2 * j + 1]) << 16);
    *(uint4*)(xf + (size_t)i * 8) = make_uint4(q[0], q[1], q[2], q[3]);
}

template<int HASB>
__global__ __launch_bounds__(256, 7) void deform_conv_fused(
    const float* __restrict__ x,
    const unsigned short* __restrict__ xf,
    const unsigned short* __restrict__ fbf,
    const unsigned short* __restrict__ wcf,
    float* __restrict__ out)
{
    // ims (cols, 18432B) overlays the conv x-tile (6912B f16, single plane).
    __shared__ __align__(16) unsigned short ims[TW * KTOT];
    __shared__ __align__(16) union UU {
        float ps2[4][TW][18];                      // conv partials
        struct { int4 c[144]; uint4 w[144]; } gs;  // gather setup (packed half2 w)
    } u;

    const int tid  = threadIdx.x;
    const int lane = tid & 63;
    const int wave = tid >> 6;
    const int pl = lane & 15;
    const int lg = lane >> 4;
    const int off_e = lg * 128 + ((pl ^ lg) << 3);
    const int off_o = lg * 128 + ((pl ^ (lg + 4)) << 3);

    // XCD swizzle: 8192 blocks, each XCD owns one image b.
    const int swz = (blockIdx.x & 7) * 1024 + (blockIdx.x >> 3);
    const int bw = swz & 7;
    const int h  = (swz >> 3) & 127;
    const int b  = swz >> 10;
    const int w0 = bw * TW;

    // -------- stage x tile [3 rows][18 px][64 ch] f16, coalesced -----------------
    // LDS index swizzle: channel chunk XOR (px&7) -> conv ds_reads <=2-way.
#pragma unroll
    for (int it = 0; it < 2; ++it) {
        int e = tid + it * 256;
        if (it == 1 && tid >= 176) break;
        int r    = (e >= 288) ? 2 : (e >= 144) ? 1 : 0;
        int rem2 = e - r * 144;
        int px   = rem2 >> 3;
        int c8   = rem2 & 7;
        int y = h + r - 1, xg = w0 + px - 1;
        int lidx = (r * 18 + px) * 64 + ((c8 * 8) ^ ((px & 7) << 3));
        uint4 val = make_uint4(0u, 0u, 0u, 0u);
        if ((unsigned)y < (unsigned)HH && (unsigned)xg < (unsigned)WW) {
            int goff = ((b * HH + y) * WW + xg) * CC + c8 * 8;
            if (HASB) {
                val = *(const uint4*)(xf + goff);
            } else {
                float4 v0 = *(const float4*)(x + goff);
                float4 v1 = *(const float4*)(x + goff + 4);
                float vv[8] = {v0.x, v0.y, v0.z, v0.w, v1.x, v1.y, v1.z, v1.w};
                unsigned q[4];
#pragma unroll
                for (int j = 0; j < 4; ++j)
                    q[j] = (unsigned)f2h(vv[2 * j]) | ((unsigned)f2h(vv[2 * j + 1]) << 16);
                val = make_uint4(q[0], q[1], q[2], q[3]);
            }
        }
        *(uint4*)(ims + lidx) = val;
    }
    __syncthreads();

    // -------- conv via MFMA (f16): A from LDS tile, B contiguous panel -----------
    const int nh = wave & 1, kh = wave >> 1;
    float4v acc = {0.f, 0.f, 0.f, 0.f};
    __builtin_amdgcn_s_setprio(1);
#pragma unroll
    for (int ks9 = 0; ks9 < 9; ++ks9) {
        const int ksg = kh * 9 + ks9;
        const int tap = ksg >> 1;
        const int cb  = (ksg & 1) * 32 + lg * 8;
        const int ky = tap / 3, kx = tap - ky * 3;
        const int px = pl + kx;
        const int base = (ky * 18 + px) * 64 + (cb ^ ((px & 7) << 3));
        half8v af = *(const half8v*)(ims + base);
        half8v bv = *(const half8v*)(wcf + ((nh * 18 + ksg) << 9) + (lane << 3));
        acc = __builtin_amdgcn_mfma_f32_16x16x32_f16(af, bv, acc, 0, 0, 0);
    }
    __builtin_amdgcn_s_setprio(0);
#pragma unroll
    for (int r = 0; r < 4; ++r)
        u.ps2[wave][lg * 4 + r][pl] = acc[r];

    // prefetch first einsum B-fragments (contiguous panel, live across barriers)
    const unsigned short* Bpf = fbf + ((wave * 18) << 9) + (lane << 3);
    half8v bp0 = *(const half8v*)(Bpf);
    half8v bp1 = *(const half8v*)(Bpf + 512);
    __syncthreads();

    // -------- setup part 1: read conv partials ------------------------------------
    const int sp = tid / 9, sk = tid - (tid / 9) * 9;
    float s_dy = 0.f, s_dx = 0.f, s_ml = 0.f;
    if (tid < 144) {
        auto rd = [&](int o) {
            int nhh = o >> 4, col = o & 15;
            return u.ps2[nhh][sp][col] + u.ps2[2 + nhh][sp][col];
        };
        s_dy = rd(2 * sk); s_dx = rd(2 * sk + 1); s_ml = rd(18 + sk);
    }
    __syncthreads();   // ps2 reads done; gs overlay + ims overwrite now safe

    // -------- setup part 2: corner bases + folded packed-f16 weights -> gs --------
    if (tid < 144) {
        float m  = 1.f / (1.f + __expf(-s_ml));
        float py = (float)(h + (sk / 3) - 1) + s_dy;
        float px = (float)(w0 + sp + (sk % 3) - 1) + s_dx;
        float y0 = floorf(py), x0 = floorf(px);
        float ly = py - y0, lx = px - x0;
        bool vy0 = (y0 >= 0.f)  && (y0 <= 127.f);
        bool vy1 = (y0 >= -1.f) && (y0 <= 126.f);
        bool vx0 = (x0 >= 0.f)  && (x0 <= 127.f);
        bool vx1 = (x0 >= -1.f) && (x0 <= 126.f);
        float wy0 = 1.f - ly, wx0 = 1.f - lx;
        int iy0 = (int)fminf(fmaxf(y0, 0.f), 127.f);
        int iy1 = (int)fminf(fmaxf(y0 + 1.f, 0.f), 127.f);
        int ix0 = (int)fminf(fmaxf(x0, 0.f), 127.f);
        int ix1 = (int)fminf(fmaxf(x0 + 1.f, 0.f), 127.f);
        int base = b * (HH * WW * CC);
        u.gs.c[tid] = make_int4(base + (iy0 * WW + ix0) * CC,
                                base + (iy0 * WW + ix1) * CC,
                                base + (iy1 * WW + ix0) * CC,
                                base + (iy1 * WW + ix1) * CC);
        u.gs.w[tid] = make_uint4(h2bits((vy0 && vx0) ? wy0 * wx0 * m : 0.f),
                                 h2bits((vy0 && vx1) ? wy0 * lx  * m : 0.f),
                                 h2bits((vy1 && vx0) ? ly  * wx0 * m : 0.f),
                                 h2bits((vy1 && vx1) ? ly  * lx  * m : 0.f));
    }
    __syncthreads();

    // -------- gather: 1152 tasks = 4 fixed iterations + 128-thread tail -----------
    // Fixed trip count + unroll lets the compiler pipeline the 16B loads across
    // iterations instead of draining vmcnt(0) each round-trip (T14/G7).
#define GATHER_BODY(T)                                                          \
    {                                                                           \
        int t = (T);                                                            \
        int pair = t >> 3, c8 = t & 7;                                          \
        int p = pair / 9, k = pair - (pair / 9) * 9;                            \
        int4  cc = u.gs.c[pair];                                                \
        uint4 wq = u.gs.w[pair];                                                \
        __half2 wv0 = bits2h(wq.x), wv1 = bits2h(wq.y);                         \
        __half2 wv2 = bits2h(wq.z), wv3 = bits2h(wq.w);                         \
        int co = c8 * 8;                                                        \
        uint4 u00 = *(const uint4*)(xf + cc.x + co);                            \
        uint4 u01 = *(const uint4*)(xf + cc.y + co);                            \
        uint4 u10 = *(const uint4*)(xf + cc.z + co);                            \
        uint4 u11 = *(const uint4*)(xf + cc.w + co);                            \
        const unsigned* a00 = (const unsigned*)&u00;                            \
        const unsigned* a01 = (const unsigned*)&u01;                            \
        const unsigned* a10 = (const unsigned*)&u10;                            \
        const unsigned* a11 = (const unsigned*)&u11;                            \
        unsigned qq[4];                                                         \
        _Pragma("unroll")                                                       \
        for (int jj = 0; jj < 4; ++jj) {                                        \
            __half2 acc2 = __hmul2(bits2h(a00[jj]), wv0);                       \
            acc2 = __hfma2(bits2h(a01[jj]), wv1, acc2);                         \
            acc2 = __hfma2(bits2h(a10[jj]), wv2, acc2);                         \
            acc2 = __hfma2(bits2h(a11[jj]), wv3, acc2);                         \
            __builtin_memcpy(&qq[jj], &acc2, 4);                                \
        }                                                                       \
        *(uint4*)(ims + frag_addr(p, k * 64 + co)) =                            \
            make_uint4(qq[0], qq[1], qq[2], qq[3]);                             \
    }

    if (HASB) {
#pragma unroll
        for (int it = 0; it < 4; ++it)
            GATHER_BODY(tid + it * 256)
        if (tid < 128)
            GATHER_BODY(1024 + tid)
    } else {
#pragma unroll
        for (int it = 0; it < 5; ++it) {
            int t = tid + it * 256;
            if (it == 4 && tid >= 128) break;
            int pair = t >> 3, c8 = t & 7;
            int p = pair / 9, k = pair - (pair / 9) * 9;
            int4  cc = u.gs.c[pair];
            uint4 wq = u.gs.w[pair];
            float wx = __half2float(bits2h(wq.x).x);
            float wy = __half2float(bits2h(wq.y).x);
            float wz = __half2float(bits2h(wq.z).x);
            float ww = __half2float(bits2h(wq.w).x);
            int co = c8 * 8;
            float r[8];
#pragma unroll
            for (int half = 0; half < 2; ++half) {
                float4 v00 = *(const float4*)(x + cc.x + co + half * 4);
                float4 v01 = *(const float4*)(x + cc.y + co + half * 4);
                float4 v10 = *(const float4*)(x + cc.z + co + half * 4);
                float4 v11 = *(const float4*)(x + cc.w + co + half * 4);
                r[half * 4 + 0] = wx * v00.x + wy * v01.x + wz * v10.x + ww * v11.x;
                r[half * 4 + 1] = wx * v00.y + wy * v01.y + wz * v10.y + ww * v11.y;
                r[half * 4 + 2] = wx * v00.z + wy * v01.z + wz * v10.z + ww * v11.z;
                r[half * 4 + 3] = wx * v00.w + wy * v01.w + wz * v10.w + ww * v11.w;
            }
            unsigned qq[4];
#pragma unroll
            for (int jj = 0; jj < 4; ++jj)
                qq[jj] = (unsigned)f2h(r[2 * jj]) | ((unsigned)f2h(r[2 * jj + 1]) << 16);
            *(uint4*)(ims + frag_addr(p, k * 64 + co)) = make_uint4(qq[0], qq[1], qq[2], qq[3]);
        }
    }
#undef GATHER_BODY
    __syncthreads();

    // -------- main einsum (f16): wave owns 16 outputs, even/odd accumulators ------
    {
        float4v accA = {0.f, 0.f, 0.f, 0.f}, accB = {0.f, 0.f, 0.f, 0.f};
        __builtin_amdgcn_s_setprio(1);
#pragma unroll
        for (int ks = 0; ks < 18; ++ks) {
            half8v a  = *(const half8v*)(ims + ks * 512 + ((ks & 1) ? off_o : off_e));
            half8v bv = (ks == 0) ? bp0 : (ks == 1) ? bp1
                      : *(const half8v*)(Bpf + (ks << 9));
            if (ks & 1) accB = __builtin_amdgcn_mfma_f32_16x16x32_f16(a, bv, accB, 0, 0, 0);
            else        accA = __builtin_amdgcn_mfma_f32_16x16x32_f16(a, bv, accA, 0, 0, 0);
        }
        __builtin_amdgcn_s_setprio(0);
        const int o = wave * 16 + pl;
        const size_t rowbase = (size_t)(b * HH + h) * WW + w0;
#pragma unroll
        for (int r = 0; r < 4; ++r) {
            int p = lg * 4 + r;
            out[(rowbase + p) * OUTC + o] = accA[r] + accB[r];
        }
    }
}

extern "C" void kernel_launch(void* const* d_in, const int* in_sizes, int n_in,
                              void* d_out, int out_size, void* d_ws, size_t ws_size,
                              hipStream_t stream) {
    const float* x    = (const float*)d_in[0];
    const float* offk = (const float*)d_in[1];
    const float* mk   = (const float*)d_in[2];
    const float* filt = (const float*)d_in[3];
    float* out = (float*)d_out;
    unsigned short* fbf = (unsigned short*)d_ws;                // 73728 B
    unsigned short* wcf = fbf + OUTC * KTOT;                    // 36864 B
    unsigned short* xf  = wcf + 32 * KTOT;                      // 16.78 MB
    size_t need = (size_t)(OUTC + 32) * KTOT * 2 + (size_t)NELEM * 2;
    int do_x = (ws_size >= need) ? 1 : 0;
    prep_all<<<144 + (do_x ? 4096 : 0), 256, 0, stream>>>(x, offk, mk, filt, fbf, wcf, xf, do_x);
    if (do_x)
        deform_conv_fused<1><<<BB * HH * (WW / TW), 256, 0, stream>>>(x, xf, fbf, wcf, out);
    else
        deform_conv_fused<0><<<BB * HH * (WW / TW), 256, 0, stream>>>(x, xf, fbf, wcf, out);
}